// Round 1
// baseline (199.805 us; speedup 1.0000x reference)
//
#include <hip/hip_runtime.h>
#include <math.h>

// VP-SDE Euler-Maruyama forward diffusion.
// x:      (64,256,64)       fp32 = 1,048,576 elems
// noise:  (100,64,256,64)   fp32
// out:    (101,64,256,64)   fp32; out[0]=x, out[t+1]=a_t*out[t]+b_t*noise[t]
//
// a_t = 1 - 0.5*beta_t*dt,  b_t = sqrt(beta_t)*sqrt(dt),
// beta_t = BETA_0 + (t/S)*(BETA_1-BETA_0), dt = 1/S.
//
// Memory-bound streaming: ~808 MB total traffic -> ~128 us floor @6.3 TB/s.

#define S_STEPS 100

__global__ __launch_bounds__(256) void vpsde_fwd_kernel(
    const float4* __restrict__ x,
    const float4* __restrict__ noise,
    float4* __restrict__ out,
    int ne4)  // number of float4 elements per timestep
{
    __shared__ float s_a[S_STEPS];
    __shared__ float s_b[S_STEPS];

    const int tid = threadIdx.x;
    if (tid < S_STEPS) {
        const float dt      = 1.0f / S_STEPS;
        const float sqrt_dt = 0.1f;  // sqrt(1/100)
        float nt   = (float)tid * dt;                    // (t-1)/S for t=1..S
        float beta = 0.1f + nt * (20.0f - 0.1f);
        s_a[tid] = 1.0f - 0.5f * beta * dt;
        s_b[tid] = sqrtf(beta) * sqrt_dt;
    }
    __syncthreads();

    const int idx = blockIdx.x * blockDim.x + tid;
    if (idx >= ne4) return;

    float4 xv = x[idx];
    out[idx] = xv;  // out[0] = x

    #pragma unroll 4
    for (int t = 0; t < S_STEPS; ++t) {
        const float a = s_a[t];
        const float b = s_b[t];
        float4 n = noise[(size_t)t * ne4 + idx];
        xv.x = fmaf(a, xv.x, b * n.x);
        xv.y = fmaf(a, xv.y, b * n.y);
        xv.z = fmaf(a, xv.z, b * n.z);
        xv.w = fmaf(a, xv.w, b * n.w);
        out[(size_t)(t + 1) * ne4 + idx] = xv;
    }
}

extern "C" void kernel_launch(void* const* d_in, const int* in_sizes, int n_in,
                              void* d_out, int out_size, void* d_ws, size_t ws_size,
                              hipStream_t stream) {
    const float* x     = (const float*)d_in[0];   // (64,256,64)
    const float* noise = (const float*)d_in[1];   // (100,64,256,64)
    float* out         = (float*)d_out;           // (101,64,256,64)

    const int ne  = in_sizes[0];       // 1,048,576 elements per timestep
    const int ne4 = ne / 4;            // 262,144 float4 per timestep

    const int block = 256;
    const int grid  = (ne4 + block - 1) / block;  // 1024 blocks

    vpsde_fwd_kernel<<<grid, block, 0, stream>>>(
        (const float4*)x, (const float4*)noise, (float4*)out, ne4);
}

// Round 4
// 178.464 us; speedup vs baseline: 1.1196x; 1.1196x over previous
//
#include <hip/hip_runtime.h>
#include <math.h>

// VP-SDE Euler-Maruyama forward diffusion (fp32).
// out[0] = x; out[t+1] = a_t * out[t] + b_t * noise[t],  t = 0..99
// a_t = 1 - 0.5*beta_t*dt, b_t = sqrt(beta_t)*sqrt(dt),
// beta_t = 0.1 + (t/100)*19.9, dt = 1/100.
//
// Pure HBM streaming: ~808 MB -> ~128 us floor @6.3 TB/s.
// R1: 199.8 us (4.04 TB/s) - dependent load->fma->store chain limited MLP.
// R2: __builtin_nontemporal_* needs clang ext_vector_type (not HIP float4).
// R3: macro param named `w` clashed with .w member access -> lambdas instead.
// Plan: double-buffered prefetch (5 loads in flight) + non-temporal ld/st.

#define S_STEPS 100
#define U 5                    // timesteps per window
#define NW (S_STEPS / U)       // 20 windows (even -> clean ping-pong)

typedef float f32x4 __attribute__((ext_vector_type(4)));

__global__ __launch_bounds__(256) void vpsde_fwd_kernel(
    const f32x4* __restrict__ x,
    const f32x4* __restrict__ noise,
    f32x4* __restrict__ out,
    int ne4)  // float4 elements per timestep
{
    __shared__ float s_a[S_STEPS];
    __shared__ float s_b[S_STEPS];

    const int tid = threadIdx.x;
    if (tid < S_STEPS) {
        const float dt = 0.01f;
        float nt_ = (float)tid * dt;          // (t-1)/S for t=1..S
        float beta = 0.1f + nt_ * 19.9f;
        s_a[tid] = 1.0f - 0.5f * beta * dt;
        s_b[tid] = sqrtf(beta) * 0.1f;        // sqrt(beta)*sqrt(dt)
    }
    __syncthreads();

    const int idx = blockIdx.x * blockDim.x + tid;
    if (idx >= ne4) return;

    const f32x4* np_ = noise + idx;
    f32x4* op_ = out + idx;

    f32x4 xv = x[idx];
    __builtin_nontemporal_store(xv, op_);     // out[0] = x

    f32x4 A[U], B[U];

    auto loadw = [&](f32x4* buf, int w0) {
        #pragma unroll
        for (int k = 0; k < U; ++k)
            buf[k] = __builtin_nontemporal_load(np_ + (size_t)(w0 + k) * ne4);
    };
    auto consume = [&](const f32x4* buf, int w0) {
        #pragma unroll
        for (int k = 0; k < U; ++k) {
            const int t = w0 + k;
            const float a = s_a[t];
            const float b = s_b[t];
            xv = a * xv + b * buf[k];          // componentwise fma
            __builtin_nontemporal_store(xv, op_ + (size_t)(t + 1) * ne4);
        }
    };

    // Ping-pong software pipeline: window w+1's loads are issued before
    // window w is consumed, so 5 independent loads stay in flight across
    // every fma+store phase.
    loadw(A, 0);
    for (int w = 0; w < NW; w += 2) {
        loadw(B, (w + 1) * U);                     // prefetch next window
        consume(A, w * U);
        if (w + 2 < NW) loadw(A, (w + 2) * U);     // prefetch window after next
        consume(B, (w + 1) * U);
    }
}

extern "C" void kernel_launch(void* const* d_in, const int* in_sizes, int n_in,
                              void* d_out, int out_size, void* d_ws, size_t ws_size,
                              hipStream_t stream) {
    const float* x     = (const float*)d_in[0];   // (64,256,64)
    const float* noise = (const float*)d_in[1];   // (100,64,256,64)
    float* out         = (float*)d_out;           // (101,64,256,64)

    const int ne  = in_sizes[0];       // 1,048,576 elements per timestep
    const int ne4 = ne / 4;            // 262,144 float4 per timestep

    const int block = 256;
    const int grid  = (ne4 + block - 1) / block;  // 1024 blocks (4/CU)

    vpsde_fwd_kernel<<<grid, block, 0, stream>>>(
        (const f32x4*)x, (const f32x4*)noise, (f32x4*)out, ne4);
}